// Round 3
// baseline (342.090 us; speedup 1.0000x reference)
//
#include <hip/hip_runtime.h>

#define BATCH 16384
#define SEQ 512

typedef float v2f __attribute__((ext_vector_type(2)));

// Activation inputs are pre-scaled at weight-load time:
//   sigmoid rows (i,f,o): W,b scaled by -log2(e)   -> sig = rcp(1+exp2(p))
//   tanh row (g):         W,b scaled by -2*log2(e) -> tanh = 2*rcp(1+exp2(p))-1
#define SIGS (-1.44269504088896f)
#define TNHS (-2.88539008177793f)

__device__ __forceinline__ float sig_pre(float p) {
    return __builtin_amdgcn_rcpf(1.0f + __builtin_amdgcn_exp2f(p));
}
__device__ __forceinline__ float tanh_pre(float p) {
    return fmaf(2.0f, __builtin_amdgcn_rcpf(1.0f + __builtin_amdgcn_exp2f(p)), -1.0f);
}
__device__ __forceinline__ float tanh_raw(float v) {
    return tanh_pre(v * TNHS);
}
__device__ __forceinline__ float bperm(int byte_addr, float v) {
    return __int_as_float(__builtin_amdgcn_ds_bpermute(byte_addr, __float_as_int(v)));
}
__device__ __forceinline__ v2f splat(float v) { return (v2f){v, v}; }

// ws[0..2559] = Wc = W2 @ W1  (collapsed MLP: no nonlinearity between W1 and W2)
// ws[2560]    = cbias = W2 . b1 + b2
__global__ __launch_bounds__(256, 1) void collapse_kernel(
    const float* __restrict__ W1, const float* __restrict__ b1,
    const float* __restrict__ W2, const float* __restrict__ b2,
    float* __restrict__ ws)
{
    const int kl = threadIdx.x & 31;   // k within block (32 columns/block)
    const int ms = threadIdx.x >> 5;   // m-slice 0..7 (64 rows each)
    const int k  = blockIdx.x * 32 + kl;
    const float* w1p = W1 + (size_t)(ms * 64) * 2560 + k;
    const float* w2p = W2 + ms * 64;
    float acc = 0.f;
    #pragma unroll 8
    for (int m = 0; m < 64; ++m) acc = fmaf(w2p[m], w1p[(size_t)m * 2560], acc);
    __shared__ float red[8][33];
    red[ms][kl] = acc;
    __syncthreads();
    if (ms == 0) {
        float s = 0.f;
        #pragma unroll
        for (int r = 0; r < 8; ++r) s += red[r][kl];
        ws[k] = s;
    }
    if (blockIdx.x == 0) {
        const int t = threadIdx.x;
        float p = fmaf(W2[t], b1[t], W2[t + 256] * b1[t + 256]);
        #pragma unroll
        for (int off = 32; off > 0; off >>= 1) p += __shfl_down(p, off);
        __shared__ float cred[4];
        if ((t & 63) == 0) cred[t >> 6] = p;
        __syncthreads();
        if (t == 0) ws[2560] = cred[0] + cred[1] + cred[2] + cred[3] + b2[0];
    }
}

// Unit-split LSTM, 2 elements per 5-lane group (ILP to hide bperm/exp latency):
// lane j owns hidden unit j of both layers for elements A and B. Weights are
// shared between A and B (loaded once, pre-scaled for the activations). Layer0
// for step t+1 is computed alongside layer1 for step t (both consume h0(t)).
// 24 elements/wave -> 683 single-wave blocks (~<=1 wave/SIMD, issue-bound).
__global__ __launch_bounds__(64)
__attribute__((amdgpu_waves_per_eu(1, 2)))
void lstm_fused_kernel(
    const float* __restrict__ x,
    const float* __restrict__ Wih0, const float* __restrict__ Whh0,
    const float* __restrict__ bih0, const float* __restrict__ bhh0,
    const float* __restrict__ Wih1, const float* __restrict__ Whh1,
    const float* __restrict__ bih1, const float* __restrict__ bhh1,
    const float* __restrict__ ws, float* __restrict__ out)
{
    const int lane = threadIdx.x;       // block = 1 wave
    const int g    = lane / 5;          // group 0..11 (12 = idle lanes)
    const int j    = lane - g * 5;      // hidden unit 0..4
    const int eA   = blockIdx.x * 24 + g * 2;
    const int eB   = eA + 1;
    const bool liveA = (g < 12) && (eA < BATCH);
    const bool liveB = (g < 12) && (eB < BATCH);
    const int ecA = min(eA, BATCH - 1);
    const int ecB = min(eB, BATCH - 1);
    const int base = g * 5;
    const int a0 = (base + 0) << 2, a1 = (base + 1) << 2, a2 = (base + 2) << 2,
              a3 = (base + 3) << 2, a4 = (base + 4) << 2;

    // per-lane weights as gate-pair float2: _01 = (i,f), _23 = (g,o); pre-scaled
    v2f wih0_01, wih0_23, bb0_01, bb0_23, bb1_01, bb1_23;
    v2f whh0_01[5], whh0_23[5], wih1_01[5], wih1_23[5], whh1_01[5], whh1_23[5];
    {
        const int r0 = 0 + j, r1 = 5 + j, r2 = 10 + j, r3 = 15 + j;
        wih0_01 = (v2f){Wih0[r0] * SIGS, Wih0[r1] * SIGS};
        wih0_23 = (v2f){Wih0[r2] * TNHS, Wih0[r3] * SIGS};
        bb0_01  = (v2f){(bih0[r0] + bhh0[r0]) * SIGS, (bih0[r1] + bhh0[r1]) * SIGS};
        bb0_23  = (v2f){(bih0[r2] + bhh0[r2]) * TNHS, (bih0[r3] + bhh0[r3]) * SIGS};
        bb1_01  = (v2f){(bih1[r0] + bhh1[r0]) * SIGS, (bih1[r1] + bhh1[r1]) * SIGS};
        bb1_23  = (v2f){(bih1[r2] + bhh1[r2]) * TNHS, (bih1[r3] + bhh1[r3]) * SIGS};
        #pragma unroll
        for (int k = 0; k < 5; ++k) {
            whh0_01[k] = (v2f){Whh0[r0 * 5 + k] * SIGS, Whh0[r1 * 5 + k] * SIGS};
            whh0_23[k] = (v2f){Whh0[r2 * 5 + k] * TNHS, Whh0[r3 * 5 + k] * SIGS};
            wih1_01[k] = (v2f){Wih1[r0 * 5 + k] * SIGS, Wih1[r1 * 5 + k] * SIGS};
            wih1_23[k] = (v2f){Wih1[r2 * 5 + k] * TNHS, Wih1[r3 * 5 + k] * SIGS};
            whh1_01[k] = (v2f){Whh1[r0 * 5 + k] * SIGS, Whh1[r1 * 5 + k] * SIGS};
            whh1_23[k] = (v2f){Whh1[r2 * 5 + k] * TNHS, Whh1[r3 * 5 + k] * SIGS};
        }
    }

    float h0A[5], h1A[5] = {0, 0, 0, 0, 0};
    float h0B[5], h1B[5] = {0, 0, 0, 0, 0};
    float c0A, c1A = 0.f, accA = 0.f;
    float c0B, c1B = 0.f, accB = 0.f;
    const float* xpA = x + (size_t)ecA * SEQ;
    const float* xpB = x + (size_t)ecB * SEQ;
    const float* wcp = ws + j;          // Wc[t*5 + j] = wcp[5t]

    float4 xbA = *(const float4*)xpA;   // x[0..3]
    float4 xbB = *(const float4*)xpB;
    float wc0 = wcp[0], wc1 = wcp[5], wc2 = wcp[10], wc3 = wcp[15];

    // prologue: layer0 at t=0 (h0 = c0 = 0)
    {
        float iA = sig_pre (fmaf(xbA.x, wih0_01.x, bb0_01.x));
        float gA = tanh_pre(fmaf(xbA.x, wih0_23.x, bb0_23.x));
        float oA = sig_pre (fmaf(xbA.x, wih0_23.y, bb0_23.y));
        c0A = iA * gA;
        float hjA = oA * tanh_raw(c0A);
        float iB = sig_pre (fmaf(xbB.x, wih0_01.x, bb0_01.x));
        float gB = tanh_pre(fmaf(xbB.x, wih0_23.x, bb0_23.x));
        float oB = sig_pre (fmaf(xbB.x, wih0_23.y, bb0_23.y));
        c0B = iB * gB;
        float hjB = oB * tanh_raw(c0B);
        h0A[0] = bperm(a0, hjA); h0A[1] = bperm(a1, hjA); h0A[2] = bperm(a2, hjA);
        h0A[3] = bperm(a3, hjA); h0A[4] = bperm(a4, hjA);
        h0B[0] = bperm(a0, hjB); h0B[1] = bperm(a1, hjB); h0B[2] = bperm(a2, hjB);
        h0B[3] = bperm(a3, hjB); h0B[4] = bperm(a4, hjB);
    }

    for (int tb = 0; tb < SEQ; tb += 4) {
        const int tn = (tb + 4) & (SEQ - 1);          // wraps on last block
        float4 xnA = *(const float4*)(xpA + tn);      // x[tb+4 .. tb+7]
        float4 xnB = *(const float4*)(xpB + tn);
        const int wb = tn * 5;
        float wn0 = wcp[wb], wn1 = wcp[wb + 5], wn2 = wcp[wb + 10], wn3 = wcp[wb + 15];

        const float xA1[4] = {xbA.y, xbA.z, xbA.w, xnA.x};   // x[t+1]
        const float xB1[4] = {xbB.y, xbB.z, xbB.w, xnB.x};
        const float wcc[4] = {wc0, wc1, wc2, wc3};           // Wc at t
        #pragma unroll
        for (int u = 0; u < 4; ++u) {
            // ---- element A: layer1 gates at t, layer0 gates at t+1 ----
            v2f QAa01 = bb1_01, QAa23 = bb1_23;
            v2f QAb01 = whh1_01[0] * splat(h1A[0]);
            v2f QAb23 = whh1_23[0] * splat(h1A[0]);
            v2f PA01 = wih0_01 * splat(xA1[u]) + bb0_01;
            v2f PA23 = wih0_23 * splat(xA1[u]) + bb0_23;
            #pragma unroll
            for (int k = 0; k < 5; ++k) {
                v2f h = splat(h0A[k]);
                QAa01 = wih1_01[k] * h + QAa01;
                QAa23 = wih1_23[k] * h + QAa23;
                PA01  = whh0_01[k] * h + PA01;
                PA23  = whh0_23[k] * h + PA23;
            }
            #pragma unroll
            for (int k = 1; k < 5; ++k) {
                v2f h = splat(h1A[k]);
                QAb01 = whh1_01[k] * h + QAb01;
                QAb23 = whh1_23[k] * h + QAb23;
            }
            v2f QA01 = QAa01 + QAb01, QA23 = QAa23 + QAb23;
            // ---- element B: same ----
            v2f QBa01 = bb1_01, QBa23 = bb1_23;
            v2f QBb01 = whh1_01[0] * splat(h1B[0]);
            v2f QBb23 = whh1_23[0] * splat(h1B[0]);
            v2f PB01 = wih0_01 * splat(xB1[u]) + bb0_01;
            v2f PB23 = wih0_23 * splat(xB1[u]) + bb0_23;
            #pragma unroll
            for (int k = 0; k < 5; ++k) {
                v2f h = splat(h0B[k]);
                QBa01 = wih1_01[k] * h + QBa01;
                QBa23 = wih1_23[k] * h + QBa23;
                PB01  = whh0_01[k] * h + PB01;
                PB23  = whh0_23[k] * h + PB23;
            }
            #pragma unroll
            for (int k = 1; k < 5; ++k) {
                v2f h = splat(h1B[k]);
                QBb01 = whh1_01[k] * h + QBb01;
                QBb23 = whh1_23[k] * h + QBb23;
            }
            v2f QB01 = QBa01 + QBb01, QB23 = QBa23 + QBb23;

            // ---- activations / state / head (A then B; chains independent) ----
            float i1A = sig_pre(QA01.x), f1A = sig_pre(QA01.y);
            float g1A = tanh_pre(QA23.x), o1A = sig_pre(QA23.y);
            c1A = fmaf(f1A, c1A, i1A * g1A);
            float hj1A = o1A * tanh_raw(c1A);
            accA = fmaf(hj1A, wcc[u], accA);
            float i0A = sig_pre(PA01.x), f0A = sig_pre(PA01.y);
            float g0A = tanh_pre(PA23.x), o0A = sig_pre(PA23.y);
            c0A = fmaf(f0A, c0A, i0A * g0A);
            float hj0A = o0A * tanh_raw(c0A);

            float i1B = sig_pre(QB01.x), f1B = sig_pre(QB01.y);
            float g1B = tanh_pre(QB23.x), o1B = sig_pre(QB23.y);
            c1B = fmaf(f1B, c1B, i1B * g1B);
            float hj1B = o1B * tanh_raw(c1B);
            accB = fmaf(hj1B, wcc[u], accB);
            float i0B = sig_pre(PB01.x), f0B = sig_pre(PB01.y);
            float g0B = tanh_pre(PB23.x), o0B = sig_pre(PB23.y);
            c0B = fmaf(f0B, c0B, i0B * g0B);
            float hj0B = o0B * tanh_raw(c0B);

            // ---- broadcasts (4 independent groups; latency overlaps with the
            //      other element's gate chains next iteration) ----
            h0A[0] = bperm(a0, hj0A); h0A[1] = bperm(a1, hj0A); h0A[2] = bperm(a2, hj0A);
            h0A[3] = bperm(a3, hj0A); h0A[4] = bperm(a4, hj0A);
            h1A[0] = bperm(a0, hj1A); h1A[1] = bperm(a1, hj1A); h1A[2] = bperm(a2, hj1A);
            h1A[3] = bperm(a3, hj1A); h1A[4] = bperm(a4, hj1A);
            h0B[0] = bperm(a0, hj0B); h0B[1] = bperm(a1, hj0B); h0B[2] = bperm(a2, hj0B);
            h0B[3] = bperm(a3, hj0B); h0B[4] = bperm(a4, hj0B);
            h1B[0] = bperm(a0, hj1B); h1B[1] = bperm(a1, hj1B); h1B[2] = bperm(a2, hj1B);
            h1B[3] = bperm(a3, hj1B); h1B[4] = bperm(a4, hj1B);
        }
        xbA = xnA; xbB = xnB;
        wc0 = wn0; wc1 = wn1; wc2 = wn2; wc3 = wn3;
    }

    // reduce the 5 per-unit partial dots within the group
    float tA = bperm(a0, accA) + bperm(a1, accA);
    tA += bperm(a2, accA) + bperm(a3, accA);
    tA += bperm(a4, accA);
    float tB = bperm(a0, accB) + bperm(a1, accB);
    tB += bperm(a2, accB) + bperm(a3, accB);
    tB += bperm(a4, accB);
    const float cb = ws[2560];
    if (liveA && j == 0) out[eA] = tA + cb;
    if (liveB && j == 0) out[eB] = tB + cb;
}

extern "C" void kernel_launch(void* const* d_in, const int* in_sizes, int n_in,
                              void* d_out, int out_size, void* d_ws, size_t ws_size,
                              hipStream_t stream) {
    const float* x    = (const float*)d_in[0];
    const float* Wih0 = (const float*)d_in[1];
    const float* Whh0 = (const float*)d_in[2];
    const float* bih0 = (const float*)d_in[3];
    const float* bhh0 = (const float*)d_in[4];
    const float* Wih1 = (const float*)d_in[5];
    const float* Whh1 = (const float*)d_in[6];
    const float* bih1 = (const float*)d_in[7];
    const float* bhh1 = (const float*)d_in[8];
    const float* W1   = (const float*)d_in[9];
    const float* b1   = (const float*)d_in[10];
    const float* W2   = (const float*)d_in[11];
    const float* b2   = (const float*)d_in[12];
    float* out = (float*)d_out;
    float* ws  = (float*)d_ws;

    collapse_kernel<<<80, 256, 0, stream>>>(W1, b1, W2, b2, ws);
    const int grid = (BATCH + 23) / 24;  // 683 blocks, 24 elements each, 1 wave/block
    lstm_fused_kernel<<<grid, 64, 0, stream>>>(x, Wih0, Whh0, bih0, bhh0,
                                               Wih1, Whh1, bih1, bhh1, ws, out);
}

// Round 4
// 304.550 us; speedup vs baseline: 1.1233x; 1.1233x over previous
//
#include <hip/hip_runtime.h>

#define BATCH 16384
#define SEQ 512

typedef float v2f __attribute__((ext_vector_type(2)));

// Activation inputs pre-scaled at weight-load time:
//   sigmoid rows (i,f,o): W,b scaled by -log2(e)   -> A = exp2(p), sig = 1/(1+A)
//   tanh row (g):         W,b scaled by -2*log2(e) -> B = exp2(p), tanh = (1-B)/(1+B)
#define SIGS (-1.44269504088896f)
#define TNHS (-2.88539008177793f)

__device__ __forceinline__ float bperm(int byte_addr, float v) {
    return __int_as_float(__builtin_amdgcn_ds_bpermute(byte_addr, __float_as_int(v)));
}
__device__ __forceinline__ v2f splat(float v) { return (v2f){v, v}; }

// One LSTM cell's activations+state with paired rcp:
//   P01 = (p_i, p_f) [SIGS-scaled], P23 = (p_g, p_o) [TNHS, SIGS].
//   sig(i)*tanh(g) = (1-B)/((1+A)(1+B));  h = sig(o)*tanh(c) = (1-Ce)/((1+O)(1+Ce)).
// 5 exp2 + 3 rcp per cell (vs 5+5 unpaired). Clamp on c-exponent: tanh is -1 to
// fp32 precision well before p=60, so min(p,60) is exact and kills inf/inf.
__device__ __forceinline__ float act_pair(v2f P01, v2f P23, float& c) {
    float A = __builtin_amdgcn_exp2f(P01.x);
    float F = __builtin_amdgcn_exp2f(P01.y);
    float B = __builtin_amdgcn_exp2f(P23.x);
    float O = __builtin_amdgcn_exp2f(P23.y);
    float rig = __builtin_amdgcn_rcpf((1.0f + A) * (1.0f + B));
    float ig  = (1.0f - B) * rig;
    float f   = __builtin_amdgcn_rcpf(1.0f + F);
    c = fmaf(f, c, ig);
    float pc = fminf(c * TNHS, 60.0f);
    float Ce = __builtin_amdgcn_exp2f(pc);
    float rho = __builtin_amdgcn_rcpf((1.0f + O) * (1.0f + Ce));
    return (1.0f - Ce) * rho;
}

// ws[0..2559] = Wc = W2 @ W1  (collapsed MLP: no nonlinearity between W1 and W2)
// ws[2560]    = cbias = W2 . b1 + b2
__global__ __launch_bounds__(256, 1) void collapse_kernel(
    const float* __restrict__ W1, const float* __restrict__ b1,
    const float* __restrict__ W2, const float* __restrict__ b2,
    float* __restrict__ ws)
{
    const int kl = threadIdx.x & 31;
    const int ms = threadIdx.x >> 5;
    const int k  = blockIdx.x * 32 + kl;
    const float* w1p = W1 + (size_t)(ms * 64) * 2560 + k;
    const float* w2p = W2 + ms * 64;
    float acc = 0.f;
    #pragma unroll 8
    for (int m = 0; m < 64; ++m) acc = fmaf(w2p[m], w1p[(size_t)m * 2560], acc);
    __shared__ float red[8][33];
    red[ms][kl] = acc;
    __syncthreads();
    if (ms == 0) {
        float s = 0.f;
        #pragma unroll
        for (int r = 0; r < 8; ++r) s += red[r][kl];
        ws[k] = s;
    }
    if (blockIdx.x == 0) {
        const int t = threadIdx.x;
        float p = fmaf(W2[t], b1[t], W2[t + 256] * b1[t + 256]);
        #pragma unroll
        for (int off = 32; off > 0; off >>= 1) p += __shfl_down(p, off);
        __shared__ float cred[4];
        if ((t & 63) == 0) cred[t >> 6] = p;
        __syncthreads();
        if (t == 0) ws[2560] = cred[0] + cred[1] + cred[2] + cred[3] + b2[0];
    }
}

// Unit-split LSTM, skew-2 pipeline: round r computes layer0 step r (consumes
// h0m1 = h0(r-1), broadcast one full round earlier) and layer1 step r-2
// (consumes h0m2 = h0(r-2), two rounds old, and h1m1 = h1(r-3), consumed LAST
// so its bpermute wait hides behind layer0's whole issue stream). All
// cross-lane latency is off the critical path; the round becomes issue-bound.
__global__ __launch_bounds__(64)
__attribute__((amdgpu_waves_per_eu(1, 2)))
void lstm_fused_kernel(
    const float* __restrict__ x,
    const float* __restrict__ Wih0, const float* __restrict__ Whh0,
    const float* __restrict__ bih0, const float* __restrict__ bhh0,
    const float* __restrict__ Wih1, const float* __restrict__ Whh1,
    const float* __restrict__ bih1, const float* __restrict__ bhh1,
    const float* __restrict__ ws, float* __restrict__ out)
{
    const int lane = threadIdx.x;       // block = 1 wave
    const int g    = lane / 5;          // group 0..11 (12 = idle lanes)
    const int j    = lane - g * 5;      // hidden unit 0..4
    const int e    = blockIdx.x * 12 + g;
    const bool live = (g < 12) && (e < BATCH);
    const int ec   = min(e, BATCH - 1);
    const int base = g * 5;
    const int a0 = (base + 0) << 2, a1 = (base + 1) << 2, a2 = (base + 2) << 2,
              a3 = (base + 3) << 2, a4 = (base + 4) << 2;

    // per-lane weights as gate-pair float2: _01 = (i,f), _23 = (g,o); pre-scaled
    v2f wih0_01, wih0_23, bb0_01, bb0_23, bb1_01, bb1_23;
    v2f whh0_01[5], whh0_23[5], wih1_01[5], wih1_23[5], whh1_01[5], whh1_23[5];
    {
        const int r0 = 0 + j, r1 = 5 + j, r2 = 10 + j, r3 = 15 + j;
        wih0_01 = (v2f){Wih0[r0] * SIGS, Wih0[r1] * SIGS};
        wih0_23 = (v2f){Wih0[r2] * TNHS, Wih0[r3] * SIGS};
        bb0_01  = (v2f){(bih0[r0] + bhh0[r0]) * SIGS, (bih0[r1] + bhh0[r1]) * SIGS};
        bb0_23  = (v2f){(bih0[r2] + bhh0[r2]) * TNHS, (bih0[r3] + bhh0[r3]) * SIGS};
        bb1_01  = (v2f){(bih1[r0] + bhh1[r0]) * SIGS, (bih1[r1] + bhh1[r1]) * SIGS};
        bb1_23  = (v2f){(bih1[r2] + bhh1[r2]) * TNHS, (bih1[r3] + bhh1[r3]) * SIGS};
        #pragma unroll
        for (int k = 0; k < 5; ++k) {
            whh0_01[k] = (v2f){Whh0[r0 * 5 + k] * SIGS, Whh0[r1 * 5 + k] * SIGS};
            whh0_23[k] = (v2f){Whh0[r2 * 5 + k] * TNHS, Whh0[r3 * 5 + k] * SIGS};
            wih1_01[k] = (v2f){Wih1[r0 * 5 + k] * SIGS, Wih1[r1 * 5 + k] * SIGS};
            wih1_23[k] = (v2f){Wih1[r2 * 5 + k] * TNHS, Wih1[r3 * 5 + k] * SIGS};
            whh1_01[k] = (v2f){Whh1[r0 * 5 + k] * SIGS, Whh1[r1 * 5 + k] * SIGS};
            whh1_23[k] = (v2f){Whh1[r2 * 5 + k] * TNHS, Whh1[r3 * 5 + k] * SIGS};
        }
    }

    float h0m1[5] = {0, 0, 0, 0, 0};   // h0(r-1)
    float h0m2[5] = {0, 0, 0, 0, 0};   // h0(r-2)
    float h1m1[5] = {0, 0, 0, 0, 0};   // h1(r-3)
    float c0 = 0.f, c1 = 0.f, acc = 0.f;
    const float* xp  = x + (size_t)ec * SEQ;
    const float* wcp = ws + j;          // Wc[t*5 + j] = wcp[5t]

    // ---- peel rounds 0,1: layer0 only ----
    {
        float x0 = xp[0];
        v2f P01 = wih0_01 * splat(x0) + bb0_01;
        v2f P23 = wih0_23 * splat(x0) + bb0_23;
        float hj0 = act_pair(P01, P23, c0);
        h0m1[0] = bperm(a0, hj0); h0m1[1] = bperm(a1, hj0); h0m1[2] = bperm(a2, hj0);
        h0m1[3] = bperm(a3, hj0); h0m1[4] = bperm(a4, hj0);
        // h0m2 stays 0 == h0(-1)
    }
    {
        float x1 = xp[1];
        v2f P01 = wih0_01 * splat(x1) + bb0_01;
        v2f P23 = wih0_23 * splat(x1) + bb0_23;
        #pragma unroll
        for (int k = 0; k < 5; ++k) {
            v2f h = splat(h0m1[k]);
            P01 = whh0_01[k] * h + P01;
            P23 = whh0_23[k] * h + P23;
        }
        float hj0 = act_pair(P01, P23, c0);
        #pragma unroll
        for (int k = 0; k < 5; ++k) h0m2[k] = h0m1[k];
        h0m1[0] = bperm(a0, hj0); h0m1[1] = bperm(a1, hj0); h0m1[2] = bperm(a2, hj0);
        h0m1[3] = bperm(a3, hj0); h0m1[4] = bperm(a4, hj0);
    }

    // x buffer for rounds r..r+3 (starts at r=2; float2 loads keep 8B align)
    float2 xa = *(const float2*)(xp + 2);
    float2 xb = *(const float2*)(xp + 4);
    float xbuf0 = xa.x, xbuf1 = xa.y, xbuf2 = xb.x, xbuf3 = xb.y;
    float wcb0 = wcp[0], wcb1 = wcp[5], wcb2 = wcp[10], wcb3 = wcp[15];

    // ---- main loop: rounds r=2..513 (128 blocks of 4) ----
    for (int r = 2; r < 514; r += 4) {
        const int tn = r + 4;
        const int o1 = min(tn, 510), o2 = min(tn + 2, 510);  // x(512/513) never used
        float2 xna = *(const float2*)(xp + o1);
        float2 xnb = *(const float2*)(xp + o2);
        const int wb = min((tn - 2) * 5, 2540);              // last prefetch unused
        float wn0 = wcp[wb], wn1 = wcp[wb + 5], wn2 = wcp[wb + 10], wn3 = wcp[wb + 15];

        const float xbuf[4] = {xbuf0, xbuf1, xbuf2, xbuf3};
        const float wcb[4]  = {wcb0, wcb1, wcb2, wcb3};
        #pragma unroll
        for (int u = 0; u < 4; ++u) {
            // ---- layer0, t0 = r+u (uses h0m1: broadcast one round ago) ----
            v2f P01 = wih0_01 * splat(xbuf[u]) + bb0_01;
            v2f P23 = wih0_23 * splat(xbuf[u]) + bb0_23;
            #pragma unroll
            for (int k = 0; k < 5; ++k) {
                v2f h = splat(h0m1[k]);
                P01 = whh0_01[k] * h + P01;
                P23 = whh0_23[k] * h + P23;
            }
            float hj0 = act_pair(P01, P23, c0);
            // ---- layer1, t1 = r+u-2: Qa (h0m2, 2 rounds old) then Qb (h1m1, last) ----
            v2f Q01 = bb1_01, Q23 = bb1_23;
            #pragma unroll
            for (int k = 0; k < 5; ++k) {
                v2f h = splat(h0m2[k]);
                Q01 = wih1_01[k] * h + Q01;
                Q23 = wih1_23[k] * h + Q23;
            }
            #pragma unroll
            for (int k = 0; k < 5; ++k) {
                v2f h = splat(h1m1[k]);
                Q01 = whh1_01[k] * h + Q01;
                Q23 = whh1_23[k] * h + Q23;
            }
            float hj1 = act_pair(Q01, Q23, c1);
            acc = fmaf(hj1, wcb[u], acc);
            // ---- shift history, then broadcasts (h0 group first, h1 second) ----
            #pragma unroll
            for (int k = 0; k < 5; ++k) h0m2[k] = h0m1[k];
            h0m1[0] = bperm(a0, hj0); h0m1[1] = bperm(a1, hj0); h0m1[2] = bperm(a2, hj0);
            h0m1[3] = bperm(a3, hj0); h0m1[4] = bperm(a4, hj0);
            h1m1[0] = bperm(a0, hj1); h1m1[1] = bperm(a1, hj1); h1m1[2] = bperm(a2, hj1);
            h1m1[3] = bperm(a3, hj1); h1m1[4] = bperm(a4, hj1);
        }
        xbuf0 = xna.x; xbuf1 = xna.y; xbuf2 = xnb.x; xbuf3 = xnb.y;
        wcb0 = wn0; wcb1 = wn1; wcb2 = wn2; wcb3 = wn3;
    }

    // reduce the 5 per-unit partial dots within the group
    float t0 = bperm(a0, acc), t1 = bperm(a1, acc), t2 = bperm(a2, acc),
          t3 = bperm(a3, acc), t4 = bperm(a4, acc);
    float total = ((t0 + t1) + (t2 + t3)) + t4;
    if (live && j == 0) out[e] = total + ws[2560];
}

extern "C" void kernel_launch(void* const* d_in, const int* in_sizes, int n_in,
                              void* d_out, int out_size, void* d_ws, size_t ws_size,
                              hipStream_t stream) {
    const float* x    = (const float*)d_in[0];
    const float* Wih0 = (const float*)d_in[1];
    const float* Whh0 = (const float*)d_in[2];
    const float* bih0 = (const float*)d_in[3];
    const float* bhh0 = (const float*)d_in[4];
    const float* Wih1 = (const float*)d_in[5];
    const float* Whh1 = (const float*)d_in[6];
    const float* bih1 = (const float*)d_in[7];
    const float* bhh1 = (const float*)d_in[8];
    const float* W1   = (const float*)d_in[9];
    const float* b1   = (const float*)d_in[10];
    const float* W2   = (const float*)d_in[11];
    const float* b2   = (const float*)d_in[12];
    float* out = (float*)d_out;
    float* ws  = (float*)d_ws;

    collapse_kernel<<<80, 256, 0, stream>>>(W1, b1, W2, b2, ws);
    const int grid = (BATCH + 11) / 12;  // 1366 blocks, 12 elements each, 1 wave/block
    lstm_fused_kernel<<<grid, 64, 0, stream>>>(x, Wih0, Whh0, bih0, bhh0,
                                               Wih1, Whh1, bih1, bhh1, ws, out);
}

// Round 5
// 302.929 us; speedup vs baseline: 1.1293x; 1.0054x over previous
//
#include <hip/hip_runtime.h>

#define BATCH 16384
#define SEQ 512

typedef float v2f __attribute__((ext_vector_type(2)));

// Activation inputs pre-scaled at weight-load time:
//   sigmoid rows (i,f,o): W,b scaled by -log2(e)   -> A = exp2(p), sig = 1/(1+A)
//   tanh row (g):         W,b scaled by -2*log2(e) -> B = exp2(p), tanh = (1-B)/(1+B)
#define SIGS (-1.44269504088896f)
#define TNHS (-2.88539008177793f)

// VALU-rate cross-lane within 4-lane quads (no DS pipe): quad_perm broadcast.
#define QPERMI(v, ctrl) __builtin_amdgcn_update_dpp(0, (v), (ctrl), 0xF, 0xF, true)
#define QPERMF(v, ctrl) __int_as_float(QPERMI(__float_as_int(v), (ctrl)))

__device__ __forceinline__ v2f splat2(float v) { return (v2f){v, v}; }
__device__ __forceinline__ v2f exp2v(v2f p) {
    return (v2f){__builtin_amdgcn_exp2f(p.x), __builtin_amdgcn_exp2f(p.y)};
}
__device__ __forceinline__ v2f rcpv(v2f p) {
    return (v2f){__builtin_amdgcn_rcpf(p.x), __builtin_amdgcn_rcpf(p.y)};
}

// Two-cell (own unit, unit 4) activation with paired rcp:
//   sig(i)*tanh(g) = (1-B)/((1+A)(1+B));  h = sig(o)*tanh(c) = (1-Ce)/((1+O)(1+Ce))
// 10 exp2 + 6 rcp per 2 cells. min(p,60) is exact (tanh saturated) and kills inf/inf.
__device__ __forceinline__ v2f act2(v2f Pi, v2f Pf, v2f Pg, v2f Po, v2f& c) {
    v2f A = exp2v(Pi), F = exp2v(Pf), B = exp2v(Pg), O = exp2v(Po);
    const v2f one = splat2(1.0f);
    v2f rig = rcpv((one + A) * (one + B));
    v2f ig  = (one - B) * rig;
    v2f f   = rcpv(one + F);
    c = f * c + ig;
    v2f pc = c * splat2(TNHS);
    pc.x = fminf(pc.x, 60.0f); pc.y = fminf(pc.y, 60.0f);
    v2f Ce = exp2v(pc);
    v2f rho = rcpv((one + O) * (one + Ce));
    return (one - Ce) * rho;
}

// Tree-shaped gate dots (short dep chains). w holds {own-row, unit4-row} pairs.
__device__ __forceinline__ v2f dot6(const v2f* w, float x, const float* h, v2f b) {
    v2f s0 = w[0] * splat2(x) + b;
    v2f s1 = w[1] * splat2(h[0]);
    s1 = w[2] * splat2(h[1]) + s1;
    v2f s2 = w[3] * splat2(h[2]);
    s2 = w[4] * splat2(h[3]) + s2;
    s0 = w[5] * splat2(h[4]) + s0;
    return (s0 + s1) + s2;
}
__device__ __forceinline__ v2f dot10(const v2f* w, const float* a, const float* h, v2f b) {
    v2f s0 = w[0] * splat2(a[0]) + b;
    v2f s1 = w[1] * splat2(a[1]);
    s1 = w[2] * splat2(a[2]) + s1;
    v2f s2 = w[3] * splat2(a[3]);
    s2 = w[4] * splat2(a[4]) + s2;
    s0 = w[5] * splat2(h[0]) + s0;
    s1 = w[6] * splat2(h[1]) + s1;
    s2 = w[7] * splat2(h[2]) + s2;
    v2f s3 = w[8] * splat2(h[3]);
    s3 = w[9] * splat2(h[4]) + s3;
    return (s0 + s1) + (s2 + s3);
}

// ws[0..2559] = Wc = W2 @ W1  (collapsed MLP: no nonlinearity between W1 and W2)
// ws[2560]    = cbias = W2 . b1 + b2
// 320 blocks (8 cols each) for CU coverage (80-block version cost ~60 us).
__global__ __launch_bounds__(256) void collapse_kernel(
    const float* __restrict__ W1, const float* __restrict__ b1,
    const float* __restrict__ W2, const float* __restrict__ b2,
    float* __restrict__ ws)
{
    const int kl = threadIdx.x & 7;    // col within block
    const int ms = threadIdx.x >> 3;   // row slice 0..31 (16 rows each)
    const int k  = blockIdx.x * 8 + kl;
    const float* w1p = W1 + (size_t)(ms * 16) * 2560 + k;
    const float* w2p = W2 + ms * 16;
    float acc = 0.f;
    #pragma unroll
    for (int m = 0; m < 16; ++m) acc = fmaf(w2p[m], w1p[(size_t)m * 2560], acc);
    __shared__ float red[32][9];
    red[ms][kl] = acc;
    __syncthreads();
    if (ms == 0) {
        float s = 0.f;
        #pragma unroll
        for (int r = 0; r < 32; ++r) s += red[r][kl];
        ws[k] = s;
    }
    if (blockIdx.x == 0) {
        const int t = threadIdx.x;
        float p = fmaf(W2[t], b1[t], W2[t + 256] * b1[t + 256]);
        #pragma unroll
        for (int off = 32; off > 0; off >>= 1) p += __shfl_down(p, off);
        __shared__ float cred[4];
        if ((t & 63) == 0) cred[t >> 6] = p;
        __syncthreads();
        if (t == 0) ws[2560] = cred[0] + cred[1] + cred[2] + cred[3] + b2[0];
    }
}

// Quad-split LSTM: 4 lanes per element (quad-aligned), lane j owns unit j of
// both layers; unit 4 rides in the .y half of every v2f (pk-math, computed
// redundantly on all 4 lanes; lane 0's copy is the one broadcast). All h
// exchange is v_mov_dpp quad_perm at VALU rate -- ZERO DS-pipe traffic (the
// ds_bpermute crossbar was the round-1..4 ~21 cyc/op chip-wide bottleneck).
// Skew-2: round r does layer0 step r and layer1 step r-2. 16 elem/wave,
// 1024 single-wave blocks = exactly 1 wave/SIMD.
__global__ __launch_bounds__(64)
__attribute__((amdgpu_waves_per_eu(1, 1)))
void lstm_fused_kernel(
    const float* __restrict__ x,
    const float* __restrict__ Wih0, const float* __restrict__ Whh0,
    const float* __restrict__ bih0, const float* __restrict__ bhh0,
    const float* __restrict__ Wih1, const float* __restrict__ Whh1,
    const float* __restrict__ bih1, const float* __restrict__ bhh1,
    const float* __restrict__ ws, float* __restrict__ out)
{
    const int lane = threadIdx.x;      // block = 1 wave
    const int q    = lane >> 2;        // element slot 0..15
    const int j    = lane & 3;         // own unit; sec unit = 4
    const int e    = blockIdx.x * 16 + q;   // BATCH % 16 == 0: always live

    // per-lane weights, v2f = {own-unit row, unit-4 row}, pre-scaled
    v2f wL0[4][6], bL0[4], wL1[4][10], bL1[4];
    {
        const float sc[4] = {SIGS, SIGS, TNHS, SIGS};
        #pragma unroll
        for (int g = 0; g < 4; ++g) {
            const int ro = g * 5 + j, rs = g * 5 + 4;
            const float s = sc[g];
            wL0[g][0] = (v2f){Wih0[ro] * s, Wih0[rs] * s};
            #pragma unroll
            for (int k = 0; k < 5; ++k)
                wL0[g][1 + k] = (v2f){Whh0[ro * 5 + k] * s, Whh0[rs * 5 + k] * s};
            bL0[g] = (v2f){(bih0[ro] + bhh0[ro]) * s, (bih0[rs] + bhh0[rs]) * s};
            #pragma unroll
            for (int k = 0; k < 5; ++k) {
                wL1[g][k]     = (v2f){Wih1[ro * 5 + k] * s, Wih1[rs * 5 + k] * s};
                wL1[g][5 + k] = (v2f){Whh1[ro * 5 + k] * s, Whh1[rs * 5 + k] * s};
            }
            bL1[g] = (v2f){(bih1[ro] + bhh1[ro]) * s, (bih1[rs] + bhh1[rs]) * s};
        }
    }

    float h0a[5] = {0, 0, 0, 0, 0};   // h0(t-1) for layer0
    float h0b[5] = {0, 0, 0, 0, 0};   // h0(t-2) for layer1
    float h1a[5] = {0, 0, 0, 0, 0};   // h1(t-3) for layer1
    v2f c0 = splat2(0.f), c1 = splat2(0.f), acc = splat2(0.f);
    const float* xp  = x + (size_t)e * SEQ;
    const float* wco = ws + j;         // own-unit Wc stream: wco[5t]
    const float* wcs = ws + 4;         // unit-4 Wc stream:   wcs[5t]

    // ---- prologue rounds 0,1: layer0 only ----
    {
        float x0 = xp[0];
        v2f Pi = dot6(wL0[0], x0, h0a, bL0[0]);
        v2f Pf = dot6(wL0[1], x0, h0a, bL0[1]);
        v2f Pg = dot6(wL0[2], x0, h0a, bL0[2]);
        v2f Po = dot6(wL0[3], x0, h0a, bL0[3]);
        v2f hp = act2(Pi, Pf, Pg, Po, c0);
        h0a[0] = QPERMF(hp.x, 0x00); h0a[1] = QPERMF(hp.x, 0x55);
        h0a[2] = QPERMF(hp.x, 0xAA); h0a[3] = QPERMF(hp.x, 0xFF);
        h0a[4] = QPERMF(hp.y, 0x00);
        // h0b stays 0 == h0(-1)
    }
    {
        float x1 = xp[1];
        v2f Pi = dot6(wL0[0], x1, h0a, bL0[0]);
        v2f Pf = dot6(wL0[1], x1, h0a, bL0[1]);
        v2f Pg = dot6(wL0[2], x1, h0a, bL0[2]);
        v2f Po = dot6(wL0[3], x1, h0a, bL0[3]);
        v2f hp = act2(Pi, Pf, Pg, Po, c0);
        #pragma unroll
        for (int k = 0; k < 5; ++k) h0b[k] = h0a[k];
        h0a[0] = QPERMF(hp.x, 0x00); h0a[1] = QPERMF(hp.x, 0x55);
        h0a[2] = QPERMF(hp.x, 0xAA); h0a[3] = QPERMF(hp.x, 0xFF);
        h0a[4] = QPERMF(hp.y, 0x00);
    }

    // x buffer for rounds r..r+3 (starts r=2; 8B-aligned float2 loads)
    float2 xa = *(const float2*)(xp + 2);
    float2 xb = *(const float2*)(xp + 4);
    float xbuf0 = xa.x, xbuf1 = xa.y, xbuf2 = xb.x, xbuf3 = xb.y;
    // Wc buffer for layer1 steps tm2 = 0..3
    float wco0 = wco[0], wco1 = wco[5], wco2 = wco[10], wco3 = wco[15];
    float wcs0 = wcs[0], wcs1 = wcs[5], wcs2 = wcs[10], wcs3 = wcs[15];

    // ---- main loop: rounds r=2..513 (128 blocks of 4) ----
    for (int r = 2; r < 514; r += 4) {
        const int tn = r + 4;
        const int o1 = min(tn, 510), o2 = min(tn + 2, 510);  // x(512/513) unused
        float2 xna = *(const float2*)(xp + o1);
        float2 xnb = *(const float2*)(xp + o2);
        const int t2 = r + 2;                                // next block's tm2 base
        const int i0 = 5 * min(t2, 511),     i1 = 5 * min(t2 + 1, 511);
        const int i2 = 5 * min(t2 + 2, 511), i3 = 5 * min(t2 + 3, 511);
        float wno0 = wco[i0], wno1 = wco[i1], wno2 = wco[i2], wno3 = wco[i3];
        float wns0 = wcs[i0], wns1 = wcs[i1], wns2 = wcs[i2], wns3 = wcs[i3];

        const float xbuf[4] = {xbuf0, xbuf1, xbuf2, xbuf3};
        const v2f wcv[4] = {(v2f){wco0, wcs0}, (v2f){wco1, wcs1},
                            (v2f){wco2, wcs2}, (v2f){wco3, wcs3}};
        #pragma unroll
        for (int u = 0; u < 4; ++u) {
            // ---- layer0, t = r+u (consumes h0a = h0(t-1)) ----
            v2f Pi0 = dot6(wL0[0], xbuf[u], h0a, bL0[0]);
            v2f Pf0 = dot6(wL0[1], xbuf[u], h0a, bL0[1]);
            v2f Pg0 = dot6(wL0[2], xbuf[u], h0a, bL0[2]);
            v2f Po0 = dot6(wL0[3], xbuf[u], h0a, bL0[3]);
            // ---- layer1, t-2 (consumes h0b = h0(t-2), h1a = h1(t-3)) ----
            v2f Pi1 = dot10(wL1[0], h0b, h1a, bL1[0]);
            v2f Pf1 = dot10(wL1[1], h0b, h1a, bL1[1]);
            v2f Pg1 = dot10(wL1[2], h0b, h1a, bL1[2]);
            v2f Po1 = dot10(wL1[3], h0b, h1a, bL1[3]);
            v2f hp0 = act2(Pi0, Pf0, Pg0, Po0, c0);
            v2f hp1 = act2(Pi1, Pf1, Pg1, Po1, c1);
            acc = hp1 * wcv[u] + acc;     // fused MLP head
            // ---- shift history, broadcast via quad DPP (VALU, no LDS) ----
            #pragma unroll
            for (int k = 0; k < 5; ++k) h0b[k] = h0a[k];
            h0a[0] = QPERMF(hp0.x, 0x00); h0a[1] = QPERMF(hp0.x, 0x55);
            h0a[2] = QPERMF(hp0.x, 0xAA); h0a[3] = QPERMF(hp0.x, 0xFF);
            h0a[4] = QPERMF(hp0.y, 0x00);
            h1a[0] = QPERMF(hp1.x, 0x00); h1a[1] = QPERMF(hp1.x, 0x55);
            h1a[2] = QPERMF(hp1.x, 0xAA); h1a[3] = QPERMF(hp1.x, 0xFF);
            h1a[4] = QPERMF(hp1.y, 0x00);
        }
        xbuf0 = xna.x; xbuf1 = xna.y; xbuf2 = xnb.x; xbuf3 = xnb.y;
        wco0 = wno0; wco1 = wno1; wco2 = wno2; wco3 = wno3;
        wcs0 = wns0; wcs1 = wns1; wcs2 = wns2; wcs3 = wns3;
    }

    // reduce: own-unit partials on lanes 0..3, unit-4 partial in lane 0's .y
    float s = acc.x + (j == 0 ? acc.y : 0.0f);
    s += QPERMF(s, 0xB1);   // quad_perm [1,0,3,2]
    s += QPERMF(s, 0x4E);   // quad_perm [2,3,0,1]
    if (j == 0) out[e] = s + ws[2560];
}

extern "C" void kernel_launch(void* const* d_in, const int* in_sizes, int n_in,
                              void* d_out, int out_size, void* d_ws, size_t ws_size,
                              hipStream_t stream) {
    const float* x    = (const float*)d_in[0];
    const float* Wih0 = (const float*)d_in[1];
    const float* Whh0 = (const float*)d_in[2];
    const float* bih0 = (const float*)d_in[3];
    const float* bhh0 = (const float*)d_in[4];
    const float* Wih1 = (const float*)d_in[5];
    const float* Whh1 = (const float*)d_in[6];
    const float* bih1 = (const float*)d_in[7];
    const float* bhh1 = (const float*)d_in[8];
    const float* W1   = (const float*)d_in[9];
    const float* b1   = (const float*)d_in[10];
    const float* W2   = (const float*)d_in[11];
    const float* b2   = (const float*)d_in[12];
    float* out = (float*)d_out;
    float* ws  = (float*)d_ws;

    collapse_kernel<<<320, 256, 0, stream>>>(W1, b1, W2, b2, ws);
    lstm_fused_kernel<<<BATCH / 16, 64, 0, stream>>>(x, Wih0, Whh0, bih0, bhh0,
                                                     Wih1, Whh1, bih1, bhh1, ws, out);
}

// Round 6
// 285.078 us; speedup vs baseline: 1.2000x; 1.0626x over previous
//
#include <hip/hip_runtime.h>

#define BATCH 16384
#define SEQ 512

typedef float v2f __attribute__((ext_vector_type(2)));

// Activation inputs pre-scaled at weight-load time:
//   sigmoid rows (i,f,o): W,b scaled by -log2(e)   -> A = exp2(p), sig = 1/(1+A)
//   tanh row (g):         W,b scaled by -2*log2(e) -> B = exp2(p), tanh = (1-B)/(1+B)
#define SIGS (-1.44269504088896f)
#define TNHS (-2.88539008177793f)

// VALU-rate cross-lane within 4-lane quads (no DS pipe).
#define QPERMI(v, ctrl) __builtin_amdgcn_update_dpp(0, (v), (ctrl), 0xF, 0xF, true)
#define QPERMF(v, ctrl) __int_as_float(QPERMI(__float_as_int(v), (ctrl)))

__device__ __forceinline__ v2f splat2(float v) { return (v2f){v, v}; }
__device__ __forceinline__ v2f exp2v(v2f p) {
    return (v2f){__builtin_amdgcn_exp2f(p.x), __builtin_amdgcn_exp2f(p.y)};
}
__device__ __forceinline__ v2f rcpv(v2f p) {
    return (v2f){__builtin_amdgcn_rcpf(p.x), __builtin_amdgcn_rcpf(p.y)};
}

// Paired-rcp LSTM cell activations (v2f = two cells):
//   sig(i)*tanh(g) = (1-B)/((1+A)(1+B));  h = sig(o)*tanh(c) = (1-Ce)/((1+O)(1+Ce))
// min(pc,60) is exact (tanh saturated long before) and kills inf/inf.
__device__ __forceinline__ v2f act2(v2f Pi, v2f Pf, v2f Pg, v2f Po, v2f& c) {
    v2f A = exp2v(Pi), F = exp2v(Pf), B = exp2v(Pg), O = exp2v(Po);
    const v2f one = splat2(1.0f);
    v2f rig = rcpv((one + A) * (one + B));
    v2f ig  = (one - B) * rig;
    v2f f   = rcpv(one + F);
    c = f * c + ig;
    v2f pc = c * splat2(TNHS);
    pc.x = fminf(pc.x, 60.0f); pc.y = fminf(pc.y, 60.0f);
    v2f Ce = exp2v(pc);
    v2f rho = rcpv((one + O) * (one + Ce));
    return (one - Ce) * rho;
}
__device__ __forceinline__ float act1(float Pi, float Pf, float Pg, float Po, float& c) {
    float A = __builtin_amdgcn_exp2f(Pi);
    float F = __builtin_amdgcn_exp2f(Pf);
    float B = __builtin_amdgcn_exp2f(Pg);
    float O = __builtin_amdgcn_exp2f(Po);
    float rig = __builtin_amdgcn_rcpf((1.0f + A) * (1.0f + B));
    float ig  = (1.0f - B) * rig;
    float f   = __builtin_amdgcn_rcpf(1.0f + F);
    c = fmaf(f, c, ig);
    float pc = fminf(c * TNHS, 60.0f);
    float Ce = __builtin_amdgcn_exp2f(pc);
    float rho = __builtin_amdgcn_rcpf((1.0f + O) * (1.0f + Ce));
    return (1.0f - Ce) * rho;
}

// ws layout (padded for the LSTM head's aligned float2 stream):
//   ws[8t + u] = Wc[t*5+u] (t<512, u<5), Wc = W2@W1 (MLP collapses: no nonlinearity)
//   ws[4096]   = cbias = W2.b1 + b2
// Coalesced: 40 blocks x (64 cols x 4 row-slices); lane-consecutive k => 256B lines.
__global__ __launch_bounds__(256) void collapse_kernel(
    const float* __restrict__ W1, const float* __restrict__ b1,
    const float* __restrict__ W2, const float* __restrict__ b2,
    float* __restrict__ ws)
{
    const int kl = threadIdx.x & 63;
    const int ms = threadIdx.x >> 6;          // 0..3, 128 rows each
    const int k  = blockIdx.x * 64 + kl;      // 40 blocks * 64 = 2560
    const float* w1p = W1 + (size_t)(ms * 128) * 2560 + k;
    const float* w2p = W2 + ms * 128;
    float acc = 0.f;
    #pragma unroll 8
    for (int m = 0; m < 128; ++m) acc = fmaf(w2p[m], w1p[(size_t)m * 2560], acc);
    __shared__ float red[4][64];
    red[ms][kl] = acc;
    __syncthreads();
    if (ms == 0) {
        float s = red[0][kl] + red[1][kl] + red[2][kl] + red[3][kl];
        ws[8 * (k / 5) + (k % 5)] = s;
    }
    if (blockIdx.x == 0) {
        const int t = threadIdx.x;
        float p = fmaf(W2[t], b1[t], W2[t + 256] * b1[t + 256]);
        #pragma unroll
        for (int off = 32; off > 0; off >>= 1) p += __shfl_down(p, off);
        __shared__ float cred[4];
        if ((t & 63) == 0) cred[t >> 6] = p;
        __syncthreads();
        if (t == 0) ws[4096] = cred[0] + cred[1] + cred[2] + cred[3] + b2[0];
    }
}

// Layer-split quad LSTM: 4 lanes per element; lanes 0,1 own layer0 unit-pairs
// (0,1)/(2,3) as v2f, lanes 2,3 own layer1 likewise; unit 4 of each layer is one
// scalar cell per lane (redundant x2). 12 cell-slots/element-step vs round-5's 16.
// Unified 11-term gate dot (x + 5*ha + 5*hb); layer0 lanes carry zero hb-weights,
// layer1 lanes zero x-weight -> one uniform instruction stream. ALL lanes share
// the broadcast regs: ha = h0(r-1) (layer0 recurrence AND layer1 input),
// hb = h1(r-2) (layer1 recurrence). Round r: layer0 does step r, layer1 step r-1.
// 16 elem/wave, 1024 single-wave blocks = 1 wave/SIMD; all cross-lane is quad DPP.
__global__ __launch_bounds__(64)
__attribute__((amdgpu_waves_per_eu(1, 1)))
void lstm_fused_kernel(
    const float* __restrict__ x,
    const float* __restrict__ Wih0, const float* __restrict__ Whh0,
    const float* __restrict__ bih0, const float* __restrict__ bhh0,
    const float* __restrict__ Wih1, const float* __restrict__ Whh1,
    const float* __restrict__ bih1, const float* __restrict__ bhh1,
    const float* __restrict__ ws, float* __restrict__ out)
{
    const int lane = threadIdx.x;       // block = 1 wave
    const int q    = lane >> 2;         // element slot 0..15
    const int j    = lane & 3;
    const int L    = j >> 1;            // 0: layer0 lanes, 1: layer1 lanes
    const int up   = (j & 1) * 2;       // unit-pair base: 0 or 2
    const int e    = blockIdx.x * 16 + q;

    // per-lane weights: v2f = unit pair (up, up+1), scalar = unit 4; pre-scaled.
    v2f   wxv[4], bv[4], wav[4][5], wbv[4][5];
    float wxs[4], bs[4], was[4][5], wbs[4][5];
    {
        const float sc[4] = {SIGS, SIGS, TNHS, SIGS};
        if (L == 0) {
            #pragma unroll
            for (int g = 0; g < 4; ++g) {
                const int r0 = g * 5 + up, r1 = r0 + 1, r4 = g * 5 + 4;
                const float s = sc[g];
                wxv[g] = (v2f){Wih0[r0] * s, Wih0[r1] * s};
                wxs[g] = Wih0[r4] * s;
                bv[g]  = (v2f){(bih0[r0] + bhh0[r0]) * s, (bih0[r1] + bhh0[r1]) * s};
                bs[g]  = (bih0[r4] + bhh0[r4]) * s;
                #pragma unroll
                for (int k = 0; k < 5; ++k) {
                    wav[g][k] = (v2f){Whh0[r0 * 5 + k] * s, Whh0[r1 * 5 + k] * s};
                    was[g][k] = Whh0[r4 * 5 + k] * s;
                    wbv[g][k] = splat2(0.f);
                    wbs[g][k] = 0.f;
                }
            }
        } else {
            #pragma unroll
            for (int g = 0; g < 4; ++g) {
                const int r0 = g * 5 + up, r1 = r0 + 1, r4 = g * 5 + 4;
                const float s = sc[g];
                wxv[g] = splat2(0.f);
                wxs[g] = 0.f;
                bv[g]  = (v2f){(bih1[r0] + bhh1[r0]) * s, (bih1[r1] + bhh1[r1]) * s};
                bs[g]  = (bih1[r4] + bhh1[r4]) * s;
                #pragma unroll
                for (int k = 0; k < 5; ++k) {
                    wav[g][k] = (v2f){Wih1[r0 * 5 + k] * s, Wih1[r1 * 5 + k] * s};
                    was[g][k] = Wih1[r4 * 5 + k] * s;
                    wbv[g][k] = (v2f){Whh1[r0 * 5 + k] * s, Whh1[r1 * 5 + k] * s};
                    wbs[g][k] = Whh1[r4 * 5 + k] * s;
                }
            }
        }
    }

    float ha[5] = {0, 0, 0, 0, 0};      // h0(r-1), shared by all lanes
    float hb[5] = {0, 0, 0, 0, 0};      // h1(r-2)
    v2f   cv = splat2(0.f), accv = splat2(0.f);
    float c4 = 0.f, acc4 = 0.f;
    const float* xp  = x + (size_t)e * SEQ;
    const float* wcb = ws + up;          // pair stream base; +8*idx

    auto round = [&](float xv, v2f wcv, float wc4) {
        v2f P[4]; float P4[4];
        #pragma unroll
        for (int g = 0; g < 4; ++g) {
            v2f t0 = wxv[g] * splat2(xv) + bv[g];
            v2f t1 = wav[g][0] * splat2(ha[0]);
            v2f t2 = wav[g][1] * splat2(ha[1]);
            t0 = wav[g][2] * splat2(ha[2]) + t0;
            t1 = wav[g][3] * splat2(ha[3]) + t1;
            t2 = wav[g][4] * splat2(ha[4]) + t2;
            t0 = wbv[g][0] * splat2(hb[0]) + t0;
            t1 = wbv[g][1] * splat2(hb[1]) + t1;
            t2 = wbv[g][2] * splat2(hb[2]) + t2;
            t0 = wbv[g][3] * splat2(hb[3]) + t0;
            t1 = wbv[g][4] * splat2(hb[4]) + t1;
            P[g] = (t0 + t1) + t2;
            float s0 = fmaf(wxs[g], xv, bs[g]);
            float s1 = was[g][0] * ha[0];
            float s2 = was[g][1] * ha[1];
            s0 = fmaf(was[g][2], ha[2], s0);
            s1 = fmaf(was[g][3], ha[3], s1);
            s2 = fmaf(was[g][4], ha[4], s2);
            s0 = fmaf(wbs[g][0], hb[0], s0);
            s1 = fmaf(wbs[g][1], hb[1], s1);
            s2 = fmaf(wbs[g][2], hb[2], s2);
            s0 = fmaf(wbs[g][3], hb[3], s0);
            s1 = fmaf(wbs[g][4], hb[4], s1);
            P4[g] = (s0 + s1) + s2;
        }
        v2f   hpv = act2(P[0], P[1], P[2], P[3], cv);
        float hp4 = act1(P4[0], P4[1], P4[2], P4[3], c4);
        // head: lanes 2,3 hold h1(r-1) units; accumulate pre-broadcast
        accv = hpv * wcv + accv;
        acc4 = fmaf(hp4, wc4, acc4);
        // broadcast: ha <- h0(r) from lanes 0,1; hb <- h1(r-1) from lanes 2,3
        ha[0] = QPERMF(hpv.x, 0x00); ha[1] = QPERMF(hpv.y, 0x00);
        ha[2] = QPERMF(hpv.x, 0x55); ha[3] = QPERMF(hpv.y, 0x55);
        ha[4] = QPERMF(hp4,   0x00);
        hb[0] = QPERMF(hpv.x, 0xAA); hb[1] = QPERMF(hpv.y, 0xAA);
        hb[2] = QPERMF(hpv.x, 0xFF); hb[3] = QPERMF(hpv.y, 0xFF);
        hb[4] = QPERMF(hp4,   0xAA);
    };

    // ---- round 0 peel: layer0 step 0; layer1 output is garbage -> reset ----
    round(xp[0], splat2(0.f), 0.f);
    if (L) { cv = splat2(0.f); c4 = 0.f; }
    #pragma unroll
    for (int k = 0; k < 5; ++k) hb[k] = 0.f;    // h1(-1) = 0

    // buffers for rounds r..r+3: x(r..r+3), Wc idx (r-1..r+2)
    float xb4[4]; v2f wv4[4]; float w44[4];
    #pragma unroll
    for (int u = 0; u < 4; ++u) {
        xb4[u] = xp[1 + u];
        wv4[u] = *(const v2f*)(wcb + 8 * u);
        w44[u] = ws[8 * u + 4];
    }

    // ---- main loop: rounds r=1..512 (128 blocks of 4) ----
    for (int r = 1; r < 513; r += 4) {
        float xn[4]; v2f wvn[4]; float w4n[4];
        #pragma unroll
        for (int u = 0; u < 4; ++u) {
            xn[u] = xp[min(r + 4 + u, SEQ - 1)];          // round-512 x unused
            const int idx = min(r + 3 + u, SEQ - 1);      // next block Wc r+3..r+6
            wvn[u] = *(const v2f*)(wcb + 8 * idx);
            w4n[u] = ws[8 * idx + 4];
        }
        #pragma unroll
        for (int u = 0; u < 4; ++u) round(xb4[u], wv4[u], w44[u]);
        #pragma unroll
        for (int u = 0; u < 4; ++u) { xb4[u] = xn[u]; wv4[u] = wvn[u]; w44[u] = w4n[u]; }
    }

    // reduce: lane2 = layer1 units (0,1) + unit4 dot-partials, lane3 = units (2,3)
    float s = accv.x + accv.y + (j == 2 ? acc4 : 0.0f);
    s += QPERMF(s, 0xB1);               // lane2 += lane3 (quad_perm [1,0,3,2])
    if (j == 2) out[e] = s + ws[4096];
}

extern "C" void kernel_launch(void* const* d_in, const int* in_sizes, int n_in,
                              void* d_out, int out_size, void* d_ws, size_t ws_size,
                              hipStream_t stream) {
    const float* x    = (const float*)d_in[0];
    const float* Wih0 = (const float*)d_in[1];
    const float* Whh0 = (const float*)d_in[2];
    const float* bih0 = (const float*)d_in[3];
    const float* bhh0 = (const float*)d_in[4];
    const float* Wih1 = (const float*)d_in[5];
    const float* Whh1 = (const float*)d_in[6];
    const float* bih1 = (const float*)d_in[7];
    const float* bhh1 = (const float*)d_in[8];
    const float* W1   = (const float*)d_in[9];
    const float* b1   = (const float*)d_in[10];
    const float* W2   = (const float*)d_in[11];
    const float* b2   = (const float*)d_in[12];
    float* out = (float*)d_out;
    float* ws  = (float*)d_ws;

    collapse_kernel<<<40, 256, 0, stream>>>(W1, b1, W2, b2, ws);
    lstm_fused_kernel<<<BATCH / 16, 64, 0, stream>>>(x, Wih0, Whh0, bih0, bhh0,
                                                     Wih1, Whh1, bih1, bhh1, ws, out);
}

// Round 7
// 257.407 us; speedup vs baseline: 1.3290x; 1.1075x over previous
//
#include <hip/hip_runtime.h>

#define BATCH 16384
#define SEQ 512

typedef float f4 __attribute__((ext_vector_type(4)));
typedef _Float16 half8 __attribute__((ext_vector_type(8)));

// Activation inputs pre-scaled into the weights:
//   sigmoid rows (i,f,o): x -log2(e)  -> A=exp2(p), sig = 1/(1+A)
//   tanh row (g):         x -2log2(e) -> B=exp2(p), tanh=(1-B)/(1+B)
#define SIGS (-1.44269504088896f)
#define TNHS (-2.88539008177793f)

union HB { unsigned int u[4]; half8 h; };

__device__ __forceinline__ float bpermf(int addr, float v) {
    return __int_as_float(__builtin_amdgcn_ds_bpermute(addr, __float_as_int(v)));
}
__device__ __forceinline__ unsigned int bpermu(int addr, unsigned int v) {
    return (unsigned int)__builtin_amdgcn_ds_bpermute(addr, (int)v);
}
__device__ __forceinline__ unsigned int h16(float v) {  // fp16 bits (RNE), low half
    return (unsigned int)__builtin_bit_cast(unsigned short, (_Float16)v);
}
// Paired-rcp LSTM cell act: 5 exp2 + 3 rcp. min(pc,60) exact (tanh saturated).
__device__ __forceinline__ float act1(float Pi, float Pf, float Pg, float Po, float& c) {
    float A = __builtin_amdgcn_exp2f(Pi);
    float F = __builtin_amdgcn_exp2f(Pf);
    float B = __builtin_amdgcn_exp2f(Pg);
    float O = __builtin_amdgcn_exp2f(Po);
    float rig = __builtin_amdgcn_rcpf((1.0f + A) * (1.0f + B));
    float ig  = (1.0f - B) * rig;
    float f   = __builtin_amdgcn_rcpf(1.0f + F);
    c = fmaf(f, c, ig);
    float pc = fminf(c * TNHS, 60.0f);
    float Ce = __builtin_amdgcn_exp2f(pc);
    float rho = __builtin_amdgcn_rcpf((1.0f + O) * (1.0f + Ce));
    return (1.0f - Ce) * rho;
}

// ws[8t+u] = Wc[t*5+u], Wc = W2@W1 (MLP collapses: no nonlinearity). ws[4096]=cbias.
__global__ __launch_bounds__(256) void collapse_kernel(
    const float* __restrict__ W1, const float* __restrict__ b1,
    const float* __restrict__ W2, const float* __restrict__ b2,
    float* __restrict__ ws)
{
    const int kl = threadIdx.x & 15;
    const int ms = threadIdx.x >> 4;          // 0..15, 32 rows each
    const int k  = blockIdx.x * 16 + kl;      // 160 blocks * 16 = 2560
    const float* w1p = W1 + (size_t)(ms * 32) * 2560 + k;
    const float* w2p = W2 + ms * 32;
    float acc = 0.f;
    #pragma unroll 8
    for (int m = 0; m < 32; ++m) acc = fmaf(w2p[m], w1p[(size_t)m * 2560], acc);
    __shared__ float red[16][17];
    red[ms][kl] = acc;
    __syncthreads();
    if (ms == 0) {
        float s = 0.f;
        #pragma unroll
        for (int r = 0; r < 16; ++r) s += red[r][kl];
        ws[8 * (k / 5) + (k % 5)] = s;
    }
    if (blockIdx.x == 0) {
        const int t = threadIdx.x;
        float p = fmaf(W2[t], b1[t], W2[t + 256] * b1[t + 256]);
        #pragma unroll
        for (int off = 32; off > 0; off >>= 1) p += __shfl_down(p, off);
        __shared__ float cred[4];
        if ((t & 63) == 0) cred[t >> 6] = p;
        __syncthreads();
        if (t == 0) ws[4096] = cred[0] + cred[1] + cred[2] + cred[3] + b2[0];
    }
}

// MFMA LSTM: 16 elements/wave on the MFMA col axis. Per round (4 mfma_16x16x32_f16):
//   L0a: gate rows 4u+gi (u=0..3)  -> lane group g holds cell L0u_g's 4 gates
//   L0b: rows 4..7  = L0u4         -> lands on lane group 1
//   L1a: rows 4u+gi = L1u0..3      (one step behind layer0)
//   L1b: rows 8..11 = L1u4         -> lands on lane group 2
// K: L0 = [x, h0(5)]; L1 = [h0(5), h1(5)] (zero-padded to 32). Biases in C.
// Acts lane-local fp32 (3 act chains; u4 cells merged by cndmask). h re-enters as
// fp16 via 6 ds_bpermute per round (one-round slack hides latency). 1024 waves.
__global__ __launch_bounds__(64)
__attribute__((amdgpu_waves_per_eu(1, 1)))
void lstm_fused_kernel(
    const float* __restrict__ x,
    const float* __restrict__ Wih0, const float* __restrict__ Whh0,
    const float* __restrict__ bih0, const float* __restrict__ bhh0,
    const float* __restrict__ Wih1, const float* __restrict__ Whh1,
    const float* __restrict__ bih1, const float* __restrict__ bhh1,
    const float* __restrict__ ws, float* __restrict__ out)
{
    const int lane = threadIdx.x;
    const int e15  = lane & 15;
    const int g    = lane >> 4;          // k-block / lane group
    const int e    = blockIdx.x * 16 + e15;
    const float sc[4] = {SIGS, SIGS, TNHS, SIGS};

    // ---- A fragments (weights, fp16): lane holds A[m=e15][k=8g+j], j=0..7 ----
    HB aL0a, aL0b, aL1a, aL1b;
    {
        const int m = e15, kb = g * 8;
        {   // L0a: row m -> cell L0u(m>>2), gate (m&3)
            const int u = m >> 2, gi = m & 3, row = gi * 5 + u;
            float w[8];
            #pragma unroll
            for (int j = 0; j < 8; ++j) {
                const int k = kb + j;
                float v = (k == 0) ? Wih0[row] : (k <= 5 ? Whh0[row * 5 + k - 1] : 0.f);
                w[j] = v * sc[gi];
            }
            #pragma unroll
            for (int d = 0; d < 4; ++d) aL0a.u[d] = h16(w[2*d]) | (h16(w[2*d+1]) << 16);
        }
        {   // L0b: rows 4..7 = L0u4, gate (m-4)
            float w[8] = {0,0,0,0,0,0,0,0};
            if (m >= 4 && m < 8) {
                const int gi = m - 4, row = gi * 5 + 4;
                #pragma unroll
                for (int j = 0; j < 8; ++j) {
                    const int k = kb + j;
                    float v = (k == 0) ? Wih0[row] : (k <= 5 ? Whh0[row * 5 + k - 1] : 0.f);
                    w[j] = v * sc[gi];
                }
            }
            #pragma unroll
            for (int d = 0; d < 4; ++d) aL0b.u[d] = h16(w[2*d]) | (h16(w[2*d+1]) << 16);
        }
        {   // L1a: row m -> cell L1u(m>>2), gate (m&3); k0-4=Wih1, k5-9=Whh1
            const int u = m >> 2, gi = m & 3, row = gi * 5 + u;
            float w[8];
            #pragma unroll
            for (int j = 0; j < 8; ++j) {
                const int k = kb + j;
                float v = (k <= 4) ? Wih1[row * 5 + k]
                        : (k <= 9 ? Whh1[row * 5 + k - 5] : 0.f);
                w[j] = v * sc[gi];
            }
            #pragma unroll
            for (int d = 0; d < 4; ++d) aL1a.u[d] = h16(w[2*d]) | (h16(w[2*d+1]) << 16);
        }
        {   // L1b: rows 8..11 = L1u4, gate (m-8)
            float w[8] = {0,0,0,0,0,0,0,0};
            if (m >= 8 && m < 12) {
                const int gi = m - 8, row = gi * 5 + 4;
                #pragma unroll
                for (int j = 0; j < 8; ++j) {
                    const int k = kb + j;
                    float v = (k <= 4) ? Wih1[row * 5 + k]
                            : (k <= 9 ? Whh1[row * 5 + k - 5] : 0.f);
                    w[j] = v * sc[gi];
                }
            }
            #pragma unroll
            for (int d = 0; d < 4; ++d) aL1b.u[d] = h16(w[2*d]) | (h16(w[2*d+1]) << 16);
        }
    }
    // ---- C fragments (biases, fp32): lane reg r -> row 4g+r ----
    f4 cL0a, cL0b, cL1a, cL1b;
    #pragma unroll
    for (int r = 0; r < 4; ++r) {
        cL0a[r] = (bih0[r*5+g] + bhh0[r*5+g]) * sc[r];
        cL0b[r] = (g == 1) ? (bih0[r*5+4] + bhh0[r*5+4]) * sc[r] : 0.f;
        cL1a[r] = (bih1[r*5+g] + bhh1[r*5+g]) * sc[r];
        cL1b[r] = (g == 2) ? (bih1[r*5+4] + bhh1[r*5+4]) * sc[r] : 0.f;
    }

    const float* xp = x + (size_t)e * SEQ;
    float c0 = 0.f, c1 = 0.f, c4 = 0.f;
    float hA = 0.f, hC = 0.f, h4 = 0.f, acc = 0.f, acc4 = 0.f;
    const bool l16 = lane < 16, l32 = lane < 32, g1 = (g == 1), g2 = (g == 2);
    const int aP1 = (e15 + 16) << 2, aP2 = (e15 + 32) << 2, aP3 = (e15 + 48) << 2;
    const int aP4 = ((lane + 16) & 63) << 2;
    const int aP5 = ((l16 ? lane + 16 : lane + 32) & 63) << 2;

    HB BL0, BL1;
    BL0.u[0] = l16 ? h16(xp[0]) : 0u;               // B(0): k0=x(0), rest 0
    BL0.u[1] = BL0.u[2] = BL0.u[3] = 0u;
    BL1.u[0] = BL1.u[1] = BL1.u[2] = BL1.u[3] = 0u;

    auto compute = [&](float wMu, float w4u) {
        f4 dA = __builtin_amdgcn_mfma_f32_16x16x32_f16(aL0a.h, BL0.h, cL0a, 0, 0, 0);
        f4 dB = __builtin_amdgcn_mfma_f32_16x16x32_f16(aL0b.h, BL0.h, cL0b, 0, 0, 0);
        f4 dC = __builtin_amdgcn_mfma_f32_16x16x32_f16(aL1a.h, BL1.h, cL1a, 0, 0, 0);
        f4 dD = __builtin_amdgcn_mfma_f32_16x16x32_f16(aL1b.h, BL1.h, cL1b, 0, 0, 0);
        hA = act1(dA[0], dA[1], dA[2], dA[3], c0);            // h0u_g
        hC = act1(dC[0], dC[1], dC[2], dC[3], c1);            // h1u_g (step-1 behind)
        float P0 = g1 ? dB[0] : dD[0], P1 = g1 ? dB[1] : dD[1];
        float P2 = g1 ? dB[2] : dD[2], P3 = g1 ? dB[3] : dD[3];
        h4 = act1(P0, P1, P2, P3, c4);                        // g1: h0u4, g2: h1u4
        acc  = fmaf(hC, wMu, acc);                            // fused MLP head
        acc4 = fmaf(h4, w4u, acc4);                           // (only g2's is used)
    };
    auto rebuild = [&](float xnext) {
        unsigned int ha = h16(hA), hc = h16(hC), hq = h16(h4), xh = h16(xnext);
        unsigned int p1 = bpermu(aP1, ha), p2 = bpermu(aP2, ha), p3 = bpermu(aP3, ha);
        unsigned int p4 = bpermu(aP4, hq), p5 = bpermu(aP5, hc), p6 = bpermu(aP2, hc);
        BL0.u[0] = l16 ? (xh | (ha << 16)) : 0u;   // k0=x, k1=h0u0
        BL0.u[1] = l16 ? (p1 | (p2 << 16)) : 0u;   // h0u1, h0u2
        BL0.u[2] = l16 ? (p3 | (p4 << 16)) : 0u;   // h0u3, h0u4
        BL0.u[3] = 0u;
        BL1.u[0] = l16 ? (ha | (p1 << 16)) : (l32 ? (p5 | (p4 << 16)) : 0u); // k8=h1u3,k9=h1u4
        BL1.u[1] = l16 ? (p2 | (p3 << 16)) : 0u;
        BL1.u[2] = l16 ? (p4 | (hc << 16)) : 0u;   // h0u4, h1u0
        BL1.u[3] = l16 ? (p5 | (p6 << 16)) : 0u;   // h1u1, h1u2
    };

    // prologue buffers for rounds 1..4
    float xs[4], wM[4], w4b[4];
    #pragma unroll
    for (int u = 0; u < 4; ++u) {
        xs[u] = xp[1 + u];
        wM[u] = ws[8 * u + g];  w4b[u] = ws[8 * u + 4];
    }
    // round 0: layer0 step 0 real; layer1 "step -1" garbage -> reset before rebuild
    compute(0.f, 0.f);
    c1 = 0.f; hC = 0.f; acc = 0.f; acc4 = 0.f;
    if (g2) { c4 = 0.f; h4 = 0.f; }
    rebuild(xs[0]);                                 // B(1) from h0(0), h1(-1)=0, x(1)

    for (int m = 1; m < 513; m += 4) {              // rounds 1..512, blocks of 4
        float xn[4], wMn[4], w4n[4];
        #pragma unroll
        for (int u = 0; u < 4; ++u) {
            xn[u] = xp[min(m + 4 + u, SEQ - 1)];
            const int idx = min(8 * (m + 3 + u), 8 * (SEQ - 1));
            wMn[u] = ws[idx + g];  w4n[u] = ws[idx + 4];
        }
        #pragma unroll
        for (int u = 0; u < 4; ++u) {
            compute(wM[u], w4b[u]);
            rebuild(u < 3 ? xs[u + 1] : xn[0]);
        }
        #pragma unroll
        for (int u = 0; u < 4; ++u) { xs[u] = xn[u]; wM[u] = wMn[u]; w4b[u] = w4n[u]; }
    }

    // reduce: element e partials live on lanes e, e+16, e+32(+u4), e+48
    float accT = acc + (g2 ? acc4 : 0.f);
    float t0 = bpermf(e15 << 2, accT);
    float t1 = bpermf((e15 + 16) << 2, accT);
    float t2 = bpermf((e15 + 32) << 2, accT);
    float t3 = bpermf((e15 + 48) << 2, accT);
    if (lane < 16) out[e] = (t0 + t1) + (t2 + t3) + ws[4096];
}

extern "C" void kernel_launch(void* const* d_in, const int* in_sizes, int n_in,
                              void* d_out, int out_size, void* d_ws, size_t ws_size,
                              hipStream_t stream) {
    const float* x    = (const float*)d_in[0];
    const float* Wih0 = (const float*)d_in[1];
    const float* Whh0 = (const float*)d_in[2];
    const float* bih0 = (const float*)d_in[3];
    const float* bhh0 = (const float*)d_in[4];
    const float* Wih1 = (const float*)d_in[5];
    const float* Whh1 = (const float*)d_in[6];
    const float* bih1 = (const float*)d_in[7];
    const float* bhh1 = (const float*)d_in[8];
    const float* W1   = (const float*)d_in[9];
    const float* b1   = (const float*)d_in[10];
    const float* W2   = (const float*)d_in[11];
    const float* b2   = (const float*)d_in[12];
    float* out = (float*)d_out;
    float* ws  = (float*)d_ws;

    collapse_kernel<<<160, 256, 0, stream>>>(W1, b1, W2, b2, ws);
    lstm_fused_kernel<<<BATCH / 16, 64, 0, stream>>>(x, Wih0, Whh0, bih0, bhh0,
                                                     Wih1, Whh1, bih1, bhh1, ws, out);
}